// Round 16
// baseline (254.332 us; speedup 1.0000x reference)
//
#include <hip/hip_runtime.h>
#include <hip/hip_bf16.h>
#include <stdint.h>

// NTXentLoss: B=4096, D=512, N=8192, tau=0.07, out = scalar mean loss.
// loss_i = -pos_i + M + log( exp(pos_i - M) + sum_{j != i,ipos} exp(s_ij - M) )
//
// R14 (2nd resubmit -- broker timeouts, experiment has never run): raise
// co-residency to 8 blocks/CU. R13 (fp8, 32 KB LDS) reached 51.5 us at
// 2.4 blocks/CU -- staging latency still serialized per block; its 4.0
// conflict-cyc/ds_read_b64 is the b64 structural floor (512 B / 128
// B-per-cyc banks), not fixable. This round: K=64 fp8 staging chunks
// (64-B rows, mod-4 rotation swizzle, 8 staging iters) -> 16 KB LDS ->
// 8 blocks/CU by wave slots (VGPR 64). Same 266 MB staged; ~3x more
// independent staging streams per CU to overlap barrier drains. Plus:
// kfinal fused into ksim (done_ctr last-block, proven R5-R7) and
// s_setprio(1) around the MFMA cluster (T5; cross-block phase diversity
// exists at 8 blocks/CU). Exact-pos fp32 hedge and group-pair XCD decode
// carried over from R13 (passed, absmax 0).

#define N_TOT   8192
#define B_HALF  4096
#define DDIM    512
#define INV_TAU 14.285714285714286f   // 1/0.07 == fixed logsumexp offset M

typedef float floatx4 __attribute__((ext_vector_type(4)));

__device__ __forceinline__ void gl2lds16(const void* g, void* l) {
    __builtin_amdgcn_global_load_lds(
        (const __attribute__((address_space(1))) void*)g,
        (__attribute__((address_space(3))) void*)l, 16, 0, 0);
}

// ---------------- kernel 1: per-pair normalize + EXACT pos logit ------------
__global__ __launch_bounds__(256) void knorm(const float* __restrict__ anchor,
                                             const float* __restrict__ positive,
                                             uint8_t* __restrict__ z,
                                             float* __restrict__ row_sums,
                                             float* __restrict__ pos_sims,
                                             unsigned* __restrict__ done_ctr) {
    const int w    = threadIdx.x >> 6;
    const int lane = threadIdx.x & 63;
    const int row  = blockIdx.x * 4 + w;          // 0..4095
    const int prow = row + B_HALF;
    if (blockIdx.x == 0 && threadIdx.x == 0) *done_ctr = 0u;

    const float* a = anchor   + (size_t)row * DDIM;
    const float* p = positive + (size_t)row * DDIM;
    float4 a0 = ((const float4*)a)[lane];
    float4 a1 = ((const float4*)a)[lane + 64];
    float4 p0 = ((const float4*)p)[lane];
    float4 p1 = ((const float4*)p)[lane + 64];

    float ssa = a0.x*a0.x + a0.y*a0.y + a0.z*a0.z + a0.w*a0.w
              + a1.x*a1.x + a1.y*a1.y + a1.z*a1.z + a1.w*a1.w;
    float ssp = p0.x*p0.x + p0.y*p0.y + p0.z*p0.z + p0.w*p0.w
              + p1.x*p1.x + p1.y*p1.y + p1.z*p1.z + p1.w*p1.w;
    float dot = a0.x*p0.x + a0.y*p0.y + a0.z*p0.z + a0.w*p0.w
              + a1.x*p1.x + a1.y*p1.y + a1.z*p1.z + a1.w*p1.w;
    #pragma unroll
    for (int m = 1; m < 64; m <<= 1) {
        ssa += __shfl_xor(ssa, m, 64);
        ssp += __shfl_xor(ssp, m, 64);
        dot += __shfl_xor(dot, m, 64);
    }
    const float inva = 1.0f / fmaxf(sqrtf(ssa), 1e-8f);
    const float invp = 1.0f / fmaxf(sqrtf(ssp), 1e-8f);
    const float psim = dot * inva * invp * INV_TAU;   // exact pos logit
    if (lane == 0) {
        pos_sims[row]  = psim;  pos_sims[prow] = psim;
        row_sums[row]  = 0.0f;  row_sums[prow] = 0.0f;
    }

    uint32_t qa0 = __builtin_amdgcn_cvt_pk_fp8_f32(a0.x*inva, a0.y*inva, 0, 0);
    qa0          = __builtin_amdgcn_cvt_pk_fp8_f32(a0.z*inva, a0.w*inva, qa0, 1);
    uint32_t qa1 = __builtin_amdgcn_cvt_pk_fp8_f32(a1.x*inva, a1.y*inva, 0, 0);
    qa1          = __builtin_amdgcn_cvt_pk_fp8_f32(a1.z*inva, a1.w*inva, qa1, 1);
    uint32_t qp0 = __builtin_amdgcn_cvt_pk_fp8_f32(p0.x*invp, p0.y*invp, 0, 0);
    qp0          = __builtin_amdgcn_cvt_pk_fp8_f32(p0.z*invp, p0.w*invp, qp0, 1);
    uint32_t qp1 = __builtin_amdgcn_cvt_pk_fp8_f32(p1.x*invp, p1.y*invp, 0, 0);
    qp1          = __builtin_amdgcn_cvt_pk_fp8_f32(p1.z*invp, p1.w*invp, qp1, 1);
    uint32_t* za = (uint32_t*)(z + (size_t)row  * DDIM);
    uint32_t* zp = (uint32_t*)(z + (size_t)prow * DDIM);
    za[lane] = qa0; za[lane + 64] = qa1;
    zp[lane] = qp0; zp[lane + 64] = qp1;
}

// ---------------- kernel 2: upper-triangle 128x128 fp8 sim tiles ------------
// 2080 tile-pairs (rt <= ct), 4 waves. LDS 16 KB (As/Bs 8 KB: 128 rows x
// 64 B, K=64 per stage, 8 staging iters, mod-4 rotation swizzle). 2 fp8
// MFMA sub-steps (K=32) per iter. Group-pair XCD decode. Pos pair excluded
// (handled exactly). Last block computes the final loss.
__global__ __launch_bounds__(256) void ksim(const uint8_t* __restrict__ z,
                                            float* __restrict__ row_sums,
                                            const float* __restrict__ pos_sims,
                                            unsigned* __restrict__ done_ctr,
                                            float* __restrict__ out) {
    const int bid = (int)blockIdx.x;
    int rem = (bid & 7) * 260 + (bid >> 3);
    int gr = 0, gc = 0;
    for (;;) {                       // <=36 scalar iterations
        const int sz = (gr == gc) ? 36 : 64;
        if (rem < sz) break;
        rem -= sz;
        if (++gc == 8) { gr++; gc = gr; }
    }
    int rt, ct;
    if (gr == gc) {
        int i = 0;
        while (rem >= 8 - i) { rem -= 8 - i; i++; }
        rt = gr * 8 + i;
        ct = gc * 8 + i + rem;
    } else {
        rt = gr * 8 + (rem >> 3);
        ct = gc * 8 + (rem & 7);
    }
    const bool diag = (rt == ct);
    const bool posb = (ct == rt + 32);

    const int r0 = rt * 128, c0 = ct * 128;
    const int tid  = threadIdx.x;
    const int w    = tid >> 6, lane = tid & 63;
    const int quad = lane >> 4, nlo = lane & 15;
    const int wrow = (w >> 1) * 64, wcol = (w & 1) * 64;

    __shared__ __align__(16) char smem[16384];
    __shared__ unsigned lastf;
    __shared__ float fsum[4];
    char* As = smem;
    char* Bs = smem + 8192;
    const char* Bbase = diag ? As : Bs;

    floatx4 acc[4][4];
    #pragma unroll
    for (int a = 0; a < 4; a++)
        #pragma unroll
        for (int b = 0; b < 4; b++) acc[a][b] = (floatx4){0.f, 0.f, 0.f, 0.f};

    const int srow = lane >> 2;   // row 0..15 within a 16-row staging chunk
    const int p    = lane & 3;    // physical 16B chunk within 64-B row

    for (int kb = 0; kb < 8; kb++) {            // K=64 fp8 per iter
        #pragma unroll
        for (int it = 0; it < 2; it++) {
            const int c  = w * 2 + it;          // 16-row chunk id, 0..7
            const int rr = c * 16 + srow;       // tile row 0..127
            const int lc = (p - rr) & 3;        // logical chunk at phys p
            gl2lds16(z + (size_t)(r0 + rr) * DDIM + kb * 64 + lc * 16,
                     As + c * 1024);
            if (!diag)
                gl2lds16(z + (size_t)(c0 + rr) * DDIM + kb * 64 + lc * 16,
                         Bs + c * 1024);
        }
        __syncthreads();

        __builtin_amdgcn_s_setprio(1);
        #pragma unroll
        for (int ks = 0; ks < 2; ks++) {        // K=32 per sub-step
            const int g  = ks * 4 + quad;       // 8-B granule index 0..7
            const int lc = g >> 1, h = g & 1;
            long af[4], bfr[4];
            #pragma unroll
            for (int mi = 0; mi < 4; mi++) {
                const int rr = wrow + mi * 16 + nlo;
                const int pc = (lc + rr) & 3;
                af[mi] = *(const long*)(As + rr * 64 + pc * 16 + h * 8);
            }
            #pragma unroll
            for (int ni = 0; ni < 4; ni++) {
                const int rr = wcol + ni * 16 + nlo;
                const int pc = (lc + rr) & 3;
                bfr[ni] = *(const long*)(Bbase + rr * 64 + pc * 16 + h * 8);
            }
            #pragma unroll
            for (int mi = 0; mi < 4; mi++)
                #pragma unroll
                for (int ni = 0; ni < 4; ni++)
                    acc[mi][ni] = __builtin_amdgcn_mfma_f32_16x16x32_fp8_fp8(
                        af[mi], bfr[ni], acc[mi][ni], 0, 0, 0);
        }
        __builtin_amdgcn_s_setprio(0);
        __syncthreads();
    }

    // epilogue: C/D layout col = lane&15, row = quad*4 + reg
    if (diag) {
        #pragma unroll
        for (int mi = 0; mi < 4; mi++) {
            #pragma unroll
            for (int reg = 0; reg < 4; reg++) {
                const int i = r0 + wrow + mi * 16 + quad * 4 + reg;
                float rs = 0.f;
                #pragma unroll
                for (int ni = 0; ni < 4; ni++) {
                    const int j2 = c0 + wcol + ni * 16 + nlo;
                    const float e = __expf(acc[mi][ni][reg] * INV_TAU - INV_TAU);
                    rs += (j2 == i) ? 0.f : e;
                }
                rs += __shfl_xor(rs, 1, 64);
                rs += __shfl_xor(rs, 2, 64);
                rs += __shfl_xor(rs, 4, 64);
                rs += __shfl_xor(rs, 8, 64);
                if (nlo == 0) atomicAdd(&row_sums[i], rs);
            }
        }
    } else {
        float cs[4] = {0.f, 0.f, 0.f, 0.f};
        #pragma unroll
        for (int mi = 0; mi < 4; mi++) {
            #pragma unroll
            for (int reg = 0; reg < 4; reg++) {
                const int i = r0 + wrow + mi * 16 + quad * 4 + reg;
                const int ipos = i ^ B_HALF;
                float rs = 0.f;
                #pragma unroll
                for (int ni = 0; ni < 4; ni++) {
                    const int j2 = c0 + wcol + ni * 16 + nlo;
                    float e = __expf(acc[mi][ni][reg] * INV_TAU - INV_TAU);
                    if (posb && j2 == ipos) e = 0.f;   // pos handled exactly
                    rs += e;
                    cs[ni] += e;
                }
                rs += __shfl_xor(rs, 1, 64);
                rs += __shfl_xor(rs, 2, 64);
                rs += __shfl_xor(rs, 4, 64);
                rs += __shfl_xor(rs, 8, 64);
                if (nlo == 0) atomicAdd(&row_sums[i], rs);
            }
        }
        #pragma unroll
        for (int ni = 0; ni < 4; ni++) {
            float c = cs[ni];
            c += __shfl_xor(c, 16, 64);
            c += __shfl_xor(c, 32, 64);
            if (quad == 0)
                atomicAdd(&row_sums[c0 + wcol + ni * 16 + nlo], c);
        }
    }

    // ---------------- fused final: last block reduces the loss --------------
    __threadfence();
    __syncthreads();
    if (tid == 0) lastf = (atomicAdd(done_ctr, 1u) == 2079u) ? 1u : 0u;
    __syncthreads();
    if (!lastf) return;
    __threadfence();
    float a = 0.f;
    for (int i = tid; i < N_TOT; i += 256) {
        const float ps = pos_sims[i];
        a += INV_TAU + __logf(row_sums[i] + __expf(ps - INV_TAU)) - ps;
    }
    #pragma unroll
    for (int m = 1; m < 64; m <<= 1) a += __shfl_xor(a, m, 64);
    if (lane == 0) fsum[w] = a;
    __syncthreads();
    if (tid == 0)
        out[0] = (fsum[0] + fsum[1] + fsum[2] + fsum[3]) * (1.0f / (float)N_TOT);
}

extern "C" void kernel_launch(void* const* d_in, const int* in_sizes, int n_in,
                              void* d_out, int out_size, void* d_ws, size_t ws_size,
                              hipStream_t stream) {
    const float* anchor   = (const float*)d_in[0];
    const float* positive = (const float*)d_in[1];
    float* out = (float*)d_out;

    char* ws = (char*)d_ws;
    uint8_t*  z        = (uint8_t*)ws;                     // 8192*512*1 = 4 MB
    float*    row_sums = (float*)(ws + 4194304);           // 32 KB
    float*    pos_sims = (float*)(ws + 4194304 + 32768);   // 32 KB
    unsigned* done_ctr = (unsigned*)(ws + 4194304 + 65536);

    knorm<<<B_HALF / 4, 256, 0, stream>>>(anchor, positive, z, row_sums,
                                          pos_sims, done_ctr);
    ksim<<<2080, 256, 0, stream>>>(z, row_sums, pos_sims, done_ctr, out);
}

// Round 17
// 110.697 us; speedup vs baseline: 2.2975x; 2.2975x over previous
//
#include <hip/hip_runtime.h>
#include <hip/hip_bf16.h>
#include <stdint.h>

// NTXentLoss: B=4096, D=512, N=8192, tau=0.07, out = scalar mean loss.
// loss_i = -pos_i + M + log( exp(pos_i - M) + sum_{j != i,ipos} exp(s_ij - M) )
//
// R17 = R13 revert (best verified: 112.6 us total, ksim 51.5 us, absmax 0).
// R14/R16 post-mortem: the co-residency experiment was invalidated by its
// riders -- (1) mod-4 swizzle on 64-B rows is 4-way bank-conflicted
// (bank = (rr&1)*16 + ((lc+rr)&3)*4: only 4 pairs per 16 lanes; conflicts
// tripled to 12.8M); (2) fused-final pushed VGPR 64->108, HALVING waves/SIMD
// (occupancy 19%, not 50%); (3) 8 small staging batches doubled exposed
// drain rounds. R13's design holds: fp8 z (halved staged bytes, 266 MB) in
// the R0 geometry (32 KB LDS, 128-B rows, 8x16B rotation swizzle at the
// ds_read_b64 structural floor, 4 staging iters, VGPR 64), exact-pos fp32
// hedge so fp8 error only enters via logsumexp averaging, group-pair XCD
// decode. After 16 rounds / 5 structural families all converging to
// 50-75 us ksim, this is the empirical optimum; ~57 us of the total is
// fixed overhead invariant to kernel-count.

#define N_TOT   8192
#define B_HALF  4096
#define DDIM    512
#define INV_TAU 14.285714285714286f   // 1/0.07 == fixed logsumexp offset M

typedef float floatx4 __attribute__((ext_vector_type(4)));

__device__ __forceinline__ void gl2lds16(const void* g, void* l) {
    __builtin_amdgcn_global_load_lds(
        (const __attribute__((address_space(1))) void*)g,
        (__attribute__((address_space(3))) void*)l, 16, 0, 0);
}

// ---------------- kernel 1: per-pair normalize + EXACT pos logit ------------
// block 256 = 4 waves; wave w owns pair (row, row+B). Computes ||a||, ||p||,
// a.p in one pass (triple shuffle-reduce), writes exact pos logit for both
// rows, quantizes both normalized rows to fp8 e4m3, zeroes row_sums.
__global__ __launch_bounds__(256) void knorm(const float* __restrict__ anchor,
                                             const float* __restrict__ positive,
                                             uint8_t* __restrict__ z,
                                             float* __restrict__ row_sums,
                                             float* __restrict__ pos_sims,
                                             float* __restrict__ out) {
    const int w    = threadIdx.x >> 6;
    const int lane = threadIdx.x & 63;
    const int row  = blockIdx.x * 4 + w;          // 0..4095
    const int prow = row + B_HALF;
    if (blockIdx.x == 0 && threadIdx.x == 0) out[0] = 0.0f;

    const float* a = anchor   + (size_t)row * DDIM;
    const float* p = positive + (size_t)row * DDIM;
    float4 a0 = ((const float4*)a)[lane];
    float4 a1 = ((const float4*)a)[lane + 64];
    float4 p0 = ((const float4*)p)[lane];
    float4 p1 = ((const float4*)p)[lane + 64];

    float ssa = a0.x*a0.x + a0.y*a0.y + a0.z*a0.z + a0.w*a0.w
              + a1.x*a1.x + a1.y*a1.y + a1.z*a1.z + a1.w*a1.w;
    float ssp = p0.x*p0.x + p0.y*p0.y + p0.z*p0.z + p0.w*p0.w
              + p1.x*p1.x + p1.y*p1.y + p1.z*p1.z + p1.w*p1.w;
    float dot = a0.x*p0.x + a0.y*p0.y + a0.z*p0.z + a0.w*p0.w
              + a1.x*p1.x + a1.y*p1.y + a1.z*p1.z + a1.w*p1.w;
    #pragma unroll
    for (int m = 1; m < 64; m <<= 1) {
        ssa += __shfl_xor(ssa, m, 64);
        ssp += __shfl_xor(ssp, m, 64);
        dot += __shfl_xor(dot, m, 64);
    }
    const float inva = 1.0f / fmaxf(sqrtf(ssa), 1e-8f);
    const float invp = 1.0f / fmaxf(sqrtf(ssp), 1e-8f);
    const float psim = dot * inva * invp * INV_TAU;   // exact pos logit
    if (lane == 0) {
        pos_sims[row]  = psim;  pos_sims[prow] = psim;
        row_sums[row]  = 0.0f;  row_sums[prow] = 0.0f;
    }

    // quantize to fp8 e4m3 (HW pack, RNE): 4 elems -> 1 uint
    uint32_t qa0 = __builtin_amdgcn_cvt_pk_fp8_f32(a0.x*inva, a0.y*inva, 0, 0);
    qa0          = __builtin_amdgcn_cvt_pk_fp8_f32(a0.z*inva, a0.w*inva, qa0, 1);
    uint32_t qa1 = __builtin_amdgcn_cvt_pk_fp8_f32(a1.x*inva, a1.y*inva, 0, 0);
    qa1          = __builtin_amdgcn_cvt_pk_fp8_f32(a1.z*inva, a1.w*inva, qa1, 1);
    uint32_t qp0 = __builtin_amdgcn_cvt_pk_fp8_f32(p0.x*invp, p0.y*invp, 0, 0);
    qp0          = __builtin_amdgcn_cvt_pk_fp8_f32(p0.z*invp, p0.w*invp, qp0, 1);
    uint32_t qp1 = __builtin_amdgcn_cvt_pk_fp8_f32(p1.x*invp, p1.y*invp, 0, 0);
    qp1          = __builtin_amdgcn_cvt_pk_fp8_f32(p1.z*invp, p1.w*invp, qp1, 1);
    uint32_t* za = (uint32_t*)(z + (size_t)row  * DDIM);
    uint32_t* zp = (uint32_t*)(z + (size_t)prow * DDIM);
    za[lane] = qa0; za[lane + 64] = qa1;
    zp[lane] = qp0; zp[lane + 64] = qp1;
}

// ---------------- kernel 2: upper-triangle 128x128 fp8 sim tiles ------------
// 2080 tile-pairs (rt <= ct). R0 geometry byte-for-byte: 4 waves, 32 KB LDS
// (As/Bs 16 KB each: 128 rows x 128 B), 8x16B rotation swizzle, sync-stage-
// sync loop -- rows hold K=128 fp8 elems, so only 4 staging iters and half
// the bytes of bf16. Inner: 4 sub-steps of mfma_f32_16x16x32_fp8_fp8.
// Group-pair XCD decode. Pos pair EXCLUDED (handled exactly in knorm).
__global__ __launch_bounds__(256, 4) void ksim(const uint8_t* __restrict__ z,
                                               float* __restrict__ row_sums) {
    const int bid = (int)blockIdx.x;
    int rem = (bid & 7) * 260 + (bid >> 3);
    int gr = 0, gc = 0;
    for (;;) {                       // <=36 scalar iterations
        const int sz = (gr == gc) ? 36 : 64;
        if (rem < sz) break;
        rem -= sz;
        if (++gc == 8) { gr++; gc = gr; }
    }
    int rt, ct;
    if (gr == gc) {
        int i = 0;
        while (rem >= 8 - i) { rem -= 8 - i; i++; }
        rt = gr * 8 + i;
        ct = gc * 8 + i + rem;
    } else {
        rt = gr * 8 + (rem >> 3);
        ct = gc * 8 + (rem & 7);
    }
    const bool diag = (rt == ct);
    const bool posb = (ct == rt + 32);

    const int r0 = rt * 128, c0 = ct * 128;
    const int tid  = threadIdx.x;
    const int w    = tid >> 6, lane = tid & 63;
    const int quad = lane >> 4, nlo = lane & 15;
    const int wrow = (w >> 1) * 64, wcol = (w & 1) * 64;

    __shared__ __align__(16) char smem[32768];
    char* As = smem;
    char* Bs = smem + 16384;
    const char* Bbase = diag ? As : Bs;

    floatx4 acc[4][4];
    #pragma unroll
    for (int a = 0; a < 4; a++)
        #pragma unroll
        for (int b = 0; b < 4; b++) acc[a][b] = (floatx4){0.f, 0.f, 0.f, 0.f};

    const int srow = lane >> 3;   // row within an 8-row staging chunk
    const int p    = lane & 7;    // physical 16B chunk within 128-B row

    for (int kb = 0; kb < 4; kb++) {           // kb*128 fp8 elems
        #pragma unroll
        for (int it = 0; it < 4; it++) {
            const int c  = w * 4 + it;          // 8-row chunk id, 0..15
            const int rr = c * 8 + srow;        // tile row 0..127
            const int lc = (p - rr) & 7;        // logical chunk at phys p
            gl2lds16(z + (size_t)(r0 + rr) * DDIM + kb * 128 + lc * 16,
                     As + c * 1024);
            if (!diag)
                gl2lds16(z + (size_t)(c0 + rr) * DDIM + kb * 128 + lc * 16,
                         Bs + c * 1024);
        }
        __syncthreads();

        #pragma unroll
        for (int ks = 0; ks < 4; ks++) {        // K=32 per sub-step
            const int g  = ks * 4 + quad;       // 8-B granule index 0..15
            const int lc = g >> 1, h = g & 1;
            long af[4], bfr[4];
            #pragma unroll
            for (int mi = 0; mi < 4; mi++) {
                const int rr = wrow + mi * 16 + nlo;
                const int pc = (lc + rr) & 7;
                af[mi] = *(const long*)(As + rr * 128 + pc * 16 + h * 8);
            }
            #pragma unroll
            for (int ni = 0; ni < 4; ni++) {
                const int rr = wcol + ni * 16 + nlo;
                const int pc = (lc + rr) & 7;
                bfr[ni] = *(const long*)(Bbase + rr * 128 + pc * 16 + h * 8);
            }
            #pragma unroll
            for (int mi = 0; mi < 4; mi++)
                #pragma unroll
                for (int ni = 0; ni < 4; ni++)
                    acc[mi][ni] = __builtin_amdgcn_mfma_f32_16x16x32_fp8_fp8(
                        af[mi], bfr[ni], acc[mi][ni], 0, 0, 0);
        }
        __syncthreads();
    }

    // epilogue: C/D layout col = lane&15, row = quad*4 + reg
    if (diag) {
        #pragma unroll
        for (int mi = 0; mi < 4; mi++) {
            #pragma unroll
            for (int reg = 0; reg < 4; reg++) {
                const int i = r0 + wrow + mi * 16 + quad * 4 + reg;
                float rs = 0.f;
                #pragma unroll
                for (int ni = 0; ni < 4; ni++) {
                    const int j2 = c0 + wcol + ni * 16 + nlo;
                    const float e = __expf(acc[mi][ni][reg] * INV_TAU - INV_TAU);
                    rs += (j2 == i) ? 0.f : e;
                }
                rs += __shfl_xor(rs, 1, 64);
                rs += __shfl_xor(rs, 2, 64);
                rs += __shfl_xor(rs, 4, 64);
                rs += __shfl_xor(rs, 8, 64);
                if (nlo == 0) atomicAdd(&row_sums[i], rs);
            }
        }
    } else {
        float cs[4] = {0.f, 0.f, 0.f, 0.f};
        #pragma unroll
        for (int mi = 0; mi < 4; mi++) {
            #pragma unroll
            for (int reg = 0; reg < 4; reg++) {
                const int i = r0 + wrow + mi * 16 + quad * 4 + reg;
                const int ipos = i ^ B_HALF;
                float rs = 0.f;
                #pragma unroll
                for (int ni = 0; ni < 4; ni++) {
                    const int j2 = c0 + wcol + ni * 16 + nlo;
                    float e = __expf(acc[mi][ni][reg] * INV_TAU - INV_TAU);
                    if (posb && j2 == ipos) e = 0.f;   // pos handled exactly
                    rs += e;
                    cs[ni] += e;
                }
                rs += __shfl_xor(rs, 1, 64);
                rs += __shfl_xor(rs, 2, 64);
                rs += __shfl_xor(rs, 4, 64);
                rs += __shfl_xor(rs, 8, 64);
                if (nlo == 0) atomicAdd(&row_sums[i], rs);
            }
        }
        #pragma unroll
        for (int ni = 0; ni < 4; ni++) {
            float c = cs[ni];
            c += __shfl_xor(c, 16, 64);
            c += __shfl_xor(c, 32, 64);
            if (quad == 0)
                atomicAdd(&row_sums[c0 + wcol + ni * 16 + nlo], c);
        }
    }
}

// ---------------- kernel 3: loss per row + mean (32 blocks, atomic out) -----
__global__ __launch_bounds__(256) void kfinal(const float* __restrict__ row_sums,
                                              const float* __restrict__ pos_sims,
                                              float* __restrict__ out) {
    const int r = blockIdx.x * 256 + threadIdx.x;
    const float ps = pos_sims[r];
    float v = INV_TAU + __logf(row_sums[r] + __expf(ps - INV_TAU)) - ps;
    #pragma unroll
    for (int m = 1; m < 64; m <<= 1) v += __shfl_xor(v, m, 64);
    __shared__ float wsum[4];
    if ((threadIdx.x & 63) == 0) wsum[threadIdx.x >> 6] = v;
    __syncthreads();
    if (threadIdx.x == 0)
        atomicAdd(out, (wsum[0] + wsum[1] + wsum[2] + wsum[3]) * (1.0f / (float)N_TOT));
}

extern "C" void kernel_launch(void* const* d_in, const int* in_sizes, int n_in,
                              void* d_out, int out_size, void* d_ws, size_t ws_size,
                              hipStream_t stream) {
    const float* anchor   = (const float*)d_in[0];
    const float* positive = (const float*)d_in[1];
    float* out = (float*)d_out;

    char* ws = (char*)d_ws;
    uint8_t* z        = (uint8_t*)ws;                      // 8192*512*1 = 4 MB
    float*   row_sums = (float*)(ws + 4194304);            // 32 KB
    float*   pos_sims = (float*)(ws + 4194304 + 32768);    // 32 KB

    knorm<<<B_HALF / 4, 256, 0, stream>>>(anchor, positive, z, row_sums,
                                          pos_sims, out);
    ksim<<<2080, 256, 0, stream>>>(z, row_sums);
    kfinal<<<N_TOT / 256, 256, 0, stream>>>(row_sums, pos_sims, out);
}